// Round 1
// baseline (382.137 us; speedup 1.0000x reference)
//
#include <hip/hip_runtime.h>
#include <hip/hip_bf16.h>
#include <math.h>

#define BB 8
#define TT 2048
#define DD 512

typedef __attribute__((ext_vector_type(8))) short bf16x8;
typedef __attribute__((ext_vector_type(4))) float f32x4;

__device__ inline float softplus_f(float v) { return log1pf(expf(v)); }

// fp32 -> bf16 round-nearest-even on bit pattern
__device__ inline unsigned short f2bf(float f) {
    unsigned int u = __float_as_uint(f);
    unsigned int r = (u + 0x7fffu + ((u >> 16) & 1u)) >> 16;
    return (unsigned short)r;
}

// ---------------- K0: per-channel prep (inv_std, normalized ema_out) ----------------
__global__ __launch_bounds__(512) void k0_prep(const float* __restrict__ ema_mean,
                                               const float* __restrict__ ema_sq,
                                               const float* __restrict__ ema_out,
                                               float* __restrict__ inv_std,
                                               float* __restrict__ ema_n) {
    __shared__ float red[8];
    int t = threadIdx.x;  // 512 threads, one per channel
    float m = ema_mean[t];
    float v = ema_sq[t] - m * m;
    v = fmaxf(v, 1e-4f);
    inv_std[t] = 1.0f / (sqrtf(v) + 1e-5f);

    float e = ema_out[t];
    float s = e * e;
#pragma unroll
    for (int off = 32; off; off >>= 1) s += __shfl_xor(s, off);
    if ((t & 63) == 0) red[t >> 6] = s;
    __syncthreads();
    if (t == 0) {
        float tot = 0.f;
        for (int i = 0; i < 8; ++i) tot += red[i];
        red[0] = 1.0f / fmaxf(sqrtf(tot), 1e-12f);
    }
    __syncthreads();
    ema_n[t] = e * red[0];
}

// ---------------- K1: per-row elementwise + reductions ----------------
// one wave (64 threads) per row of D=512; 8 elems/thread
__global__ __launch_bounds__(64) void k1_elem(
    const float* __restrict__ x, const float* __restrict__ ema_mean,
    const float* __restrict__ inv_std, const float* __restrict__ ema_n,
    const float* __restrict__ p_log_tau, const float* __restrict__ p_lbu,
    const float* __restrict__ p_lbd, const float* __restrict__ p_lg,
    float* __restrict__ out, unsigned short* __restrict__ xn) {
    const int row = blockIdx.x;
    const int lane = threadIdx.x;
    const size_t base = (size_t)row * DD;

    const float tau = expf(p_log_tau[0]);
    const float beta_up = softplus_f(p_lbu[0]);
    const float beta_dn = softplus_f(p_lbd[0]);
    const float gamma = softplus_f(p_lg[0]);

    float xv[8], pg[8];
    float sx2 = 0.f, so2 = 0.f, sod = 0.f;
#pragma unroll
    for (int c = 0; c < 2; ++c) {
        const int j0 = c * 256 + lane * 4;
        float4 xx = *reinterpret_cast<const float4*>(x + base + j0);
        float vv[4] = {xx.x, xx.y, xx.z, xx.w};
#pragma unroll
        for (int q = 0; q < 4; ++q) {
            const int d = j0 + q;
            const int e = c * 4 + q;
            float xf = vv[q];
            xv[e] = xf;
            // gelu (tanh approx)
            float x3 = xf * xf * xf;
            float gl = 0.5f * xf * (1.0f + tanhf(0.7978845608028654f * (xf + 0.044715f * x3)));
            // z-gate
            float z = (xf - ema_mean[d]) * inv_std[d];
            float th = tanhf(gamma * z);
            float up = beta_up * fmaxf(th, 0.0f);
            float dn = beta_dn * fmaxf(-th, 0.0f);
            float gh = fminf(fmaxf(1.0f + up - dn, 0.05f), 8.0f);
            pg[e] = gl * gh;
            sx2 += xf * xf;
            so2 += gl * gl;
            sod += gl * ema_n[d];
        }
    }
#pragma unroll
    for (int off = 32; off; off >>= 1) {
        sx2 += __shfl_xor(sx2, off);
        so2 += __shfl_xor(so2, off);
        sod += __shfl_xor(sod, off);
    }
    const float inv_xnorm = 1.0f / fmaxf(sqrtf(sx2), 1e-12f);
    float cosv = sod / fmaxf(sqrtf(so2), 1e-12f);
    cosv = fminf(fmaxf(cosv, -1.0f), 1.0f);
    const float gcos = expf(-tau * cosv);

#pragma unroll
    for (int c = 0; c < 2; ++c) {
        const int j0 = c * 256 + lane * 4;
        float4 ov;
        ov.x = pg[c * 4 + 0] * gcos;
        ov.y = pg[c * 4 + 1] * gcos;
        ov.z = pg[c * 4 + 2] * gcos;
        ov.w = pg[c * 4 + 3] * gcos;
        *reinterpret_cast<float4*>(out + base + j0) = ov;
        ushort4 xb;
        xb.x = f2bf(xv[c * 4 + 0] * inv_xnorm);
        xb.y = f2bf(xv[c * 4 + 1] * inv_xnorm);
        xb.z = f2bf(xv[c * 4 + 2] * inv_xnorm);
        xb.w = f2bf(xv[c * 4 + 3] * inv_xnorm);
        *reinterpret_cast<ushort4*>(xn + base + j0) = xb;
    }
}

// ---------------- K2: nearest-neighbor sim row-max via MFMA ----------------
// block = 256 threads = 4 waves; each wave owns 16 rows (one 16-row m-band).
// A fragments (16 rows x K=512) held in registers (64 VGPR); B streamed from L2.
__global__ __launch_bounds__(256) void k2_nn(const unsigned short* __restrict__ xn,
                                             const float* __restrict__ p_lsn,
                                             const float* __restrict__ p_lwn,
                                             float* __restrict__ gate_nn) {
    const int wave = threadIdx.x >> 6;
    const int lane = threadIdx.x & 63;
    const int tile = blockIdx.x & 31;  // 32 tiles of 64 rows per batch
    const int b = blockIdx.x >> 5;     // 8 batches
    const int m0 = tile * 64 + wave * 16;  // batch-local row base for this wave
    const size_t bbase = (size_t)b * TT * DD;

    const float sigma_nn = softplus_f(p_lsn[0]);
    const float w_nn = softplus_f(p_lwn[0]);

    const int r15 = lane & 15;
    const int kgrp = lane >> 4;  // 0..3

    // A fragments: A[m][k], m = lane&15, k = kk*32 + kgrp*8 + j
    bf16x8 a[16];
    const unsigned short* arow = xn + bbase + (size_t)(m0 + r15) * DD + kgrp * 8;
#pragma unroll
    for (int kk = 0; kk < 16; ++kk)
        a[kk] = *reinterpret_cast<const bf16x8*>(arow + kk * 32);

    float rmax[4] = {-2.f, -2.f, -2.f, -2.f};

    for (int s0 = 0; s0 < TT; s0 += 16) {
        const unsigned short* brow = xn + bbase + (size_t)(s0 + r15) * DD + kgrp * 8;
        f32x4 acc = {0.f, 0.f, 0.f, 0.f};
#pragma unroll
        for (int kk = 0; kk < 16; ++kk) {
            bf16x8 bf = *reinterpret_cast<const bf16x8*>(brow + kk * 32);
            acc = __builtin_amdgcn_mfma_f32_16x16x32_bf16(a[kk], bf, acc, 0, 0, 0);
        }
        // D layout: col = lane&15, row = (lane>>4)*4 + r  [m89-verified]
        if (s0 == m0) {
#pragma unroll
            for (int r = 0; r < 4; ++r) {
                int i = kgrp * 4 + r;
                float v = (i == r15) ? -2.0f : acc[r];
                rmax[r] = fmaxf(rmax[r], v);
            }
        } else {
#pragma unroll
            for (int r = 0; r < 4; ++r) rmax[r] = fmaxf(rmax[r], acc[r]);
        }
    }
    // reduce max across the 16 col-lanes (same kgrp group)
#pragma unroll
    for (int r = 0; r < 4; ++r) {
        float v = rmax[r];
        v = fmaxf(v, __shfl_xor(v, 1));
        v = fmaxf(v, __shfl_xor(v, 2));
        v = fmaxf(v, __shfl_xor(v, 4));
        v = fmaxf(v, __shfl_xor(v, 8));
        rmax[r] = v;
    }
    if (r15 == 0) {
#pragma unroll
        for (int r = 0; r < 4; ++r) {
            int row = m0 + kgrp * 4 + r;
            float novelty = 0.5f * (1.0f - rmax[r]);
            float surp = tanhf(sigma_nn * novelty);
            gate_nn[b * TT + row] = 1.0f + w_nn * surp;
        }
    }
}

// ---------------- K3: scale rows by gate_nn ----------------
__global__ __launch_bounds__(256) void k3_scale(float* __restrict__ out,
                                                const float* __restrict__ gate) {
    size_t i = (size_t)blockIdx.x * blockDim.x + threadIdx.x;  // float4 index
    float4* o4 = reinterpret_cast<float4*>(out);
    int row = (int)(i >> 7);  // 128 float4 per row of 512
    float g = gate[row];
    float4 v = o4[i];
    v.x *= g; v.y *= g; v.z *= g; v.w *= g;
    o4[i] = v;
}

extern "C" void kernel_launch(void* const* d_in, const int* in_sizes, int n_in,
                              void* d_out, int out_size, void* d_ws, size_t ws_size,
                              hipStream_t stream) {
    const float* x = (const float*)d_in[0];
    const float* ema_mean = (const float*)d_in[1];
    const float* ema_sq = (const float*)d_in[2];
    const float* ema_out = (const float*)d_in[3];
    const float* log_tau = (const float*)d_in[4];
    const float* log_beta_up = (const float*)d_in[5];
    const float* log_beta_dn = (const float*)d_in[6];
    const float* log_gamma = (const float*)d_in[7];
    const float* log_sigma_nn = (const float*)d_in[8];
    const float* log_w_nn = (const float*)d_in[9];

    // ws layout: XN bf16 [B*T*D] (16.78 MB) | inv_std f32[512] | ema_n f32[512] | gate f32[B*T]
    char* ws = (char*)d_ws;
    unsigned short* XN = (unsigned short*)ws;
    float* inv_std = (float*)(ws + 16777216);
    float* ema_n = (float*)(ws + 16777216 + 2048);
    float* gate = (float*)(ws + 16777216 + 4096);
    float* out = (float*)d_out;

    hipLaunchKernelGGL(k0_prep, dim3(1), dim3(512), 0, stream, ema_mean, ema_sq, ema_out,
                       inv_std, ema_n);
    hipLaunchKernelGGL(k1_elem, dim3(BB * TT), dim3(64), 0, stream, x, ema_mean, inv_std, ema_n,
                       log_tau, log_beta_up, log_beta_dn, log_gamma, out, XN);
    hipLaunchKernelGGL(k2_nn, dim3(BB * (TT / 64)), dim3(256), 0, stream, XN, log_sigma_nn,
                       log_w_nn, gate);
    hipLaunchKernelGGL(k3_scale, dim3((BB * TT * DD / 4) / 256), dim3(256), 0, stream, out, gate);
}

// Round 2
// 290.603 us; speedup vs baseline: 1.3150x; 1.3150x over previous
//
#include <hip/hip_runtime.h>
#include <hip/hip_bf16.h>
#include <math.h>

#define BB 8
#define TT 2048
#define DD 512
#define NSPLIT 4
#define SCHUNK (TT / NSPLIT)  // 512

typedef __attribute__((ext_vector_type(8))) short bf16x8;
typedef __attribute__((ext_vector_type(4))) float f32x4;

__device__ inline float softplus_f(float v) { return log1pf(expf(v)); }

// fp32 -> bf16 round-nearest-even on bit pattern
__device__ inline unsigned short f2bf(float f) {
    unsigned int u = __float_as_uint(f);
    unsigned int r = (u + 0x7fffu + ((u >> 16) & 1u)) >> 16;
    return (unsigned short)r;
}

// ---------------- K0: per-channel prep (inv_std, normalized ema_out) ----------------
__global__ __launch_bounds__(512) void k0_prep(const float* __restrict__ ema_mean,
                                               const float* __restrict__ ema_sq,
                                               const float* __restrict__ ema_out,
                                               float* __restrict__ inv_std,
                                               float* __restrict__ ema_n) {
    __shared__ float red[8];
    int t = threadIdx.x;  // 512 threads, one per channel
    float m = ema_mean[t];
    float v = ema_sq[t] - m * m;
    v = fmaxf(v, 1e-4f);
    inv_std[t] = 1.0f / (sqrtf(v) + 1e-5f);

    float e = ema_out[t];
    float s = e * e;
#pragma unroll
    for (int off = 32; off; off >>= 1) s += __shfl_xor(s, off);
    if ((t & 63) == 0) red[t >> 6] = s;
    __syncthreads();
    if (t == 0) {
        float tot = 0.f;
        for (int i = 0; i < 8; ++i) tot += red[i];
        red[0] = 1.0f / fmaxf(sqrtf(tot), 1e-12f);
    }
    __syncthreads();
    ema_n[t] = e * red[0];
}

// ---------------- K1: per-row elementwise + reductions ----------------
// one wave (64 threads) per row of D=512; 8 elems/thread
__global__ __launch_bounds__(64) void k1_elem(
    const float* __restrict__ x, const float* __restrict__ ema_mean,
    const float* __restrict__ inv_std, const float* __restrict__ ema_n,
    const float* __restrict__ p_log_tau, const float* __restrict__ p_lbu,
    const float* __restrict__ p_lbd, const float* __restrict__ p_lg,
    float* __restrict__ out, unsigned short* __restrict__ xn) {
    const int row = blockIdx.x;
    const int lane = threadIdx.x;
    const size_t base = (size_t)row * DD;

    const float tau = expf(p_log_tau[0]);
    const float beta_up = softplus_f(p_lbu[0]);
    const float beta_dn = softplus_f(p_lbd[0]);
    const float gamma = softplus_f(p_lg[0]);

    float xv[8], pg[8];
    float sx2 = 0.f, so2 = 0.f, sod = 0.f;
#pragma unroll
    for (int c = 0; c < 2; ++c) {
        const int j0 = c * 256 + lane * 4;
        float4 xx = *reinterpret_cast<const float4*>(x + base + j0);
        float vv[4] = {xx.x, xx.y, xx.z, xx.w};
#pragma unroll
        for (int q = 0; q < 4; ++q) {
            const int d = j0 + q;
            const int e = c * 4 + q;
            float xf = vv[q];
            xv[e] = xf;
            // gelu (tanh approx)
            float x3 = xf * xf * xf;
            float gl = 0.5f * xf * (1.0f + tanhf(0.7978845608028654f * (xf + 0.044715f * x3)));
            // z-gate
            float z = (xf - ema_mean[d]) * inv_std[d];
            float th = tanhf(gamma * z);
            float up = beta_up * fmaxf(th, 0.0f);
            float dn = beta_dn * fmaxf(-th, 0.0f);
            float gh = fminf(fmaxf(1.0f + up - dn, 0.05f), 8.0f);
            pg[e] = gl * gh;
            sx2 += xf * xf;
            so2 += gl * gl;
            sod += gl * ema_n[d];
        }
    }
#pragma unroll
    for (int off = 32; off; off >>= 1) {
        sx2 += __shfl_xor(sx2, off);
        so2 += __shfl_xor(so2, off);
        sod += __shfl_xor(sod, off);
    }
    const float inv_xnorm = 1.0f / fmaxf(sqrtf(sx2), 1e-12f);
    float cosv = sod / fmaxf(sqrtf(so2), 1e-12f);
    cosv = fminf(fmaxf(cosv, -1.0f), 1.0f);
    const float gcos = expf(-tau * cosv);

#pragma unroll
    for (int c = 0; c < 2; ++c) {
        const int j0 = c * 256 + lane * 4;
        float4 ov;
        ov.x = pg[c * 4 + 0] * gcos;
        ov.y = pg[c * 4 + 1] * gcos;
        ov.z = pg[c * 4 + 2] * gcos;
        ov.w = pg[c * 4 + 3] * gcos;
        *reinterpret_cast<float4*>(out + base + j0) = ov;
        ushort4 xb;
        xb.x = f2bf(xv[c * 4 + 0] * inv_xnorm);
        xb.y = f2bf(xv[c * 4 + 1] * inv_xnorm);
        xb.z = f2bf(xv[c * 4 + 2] * inv_xnorm);
        xb.w = f2bf(xv[c * 4 + 3] * inv_xnorm);
        *reinterpret_cast<ushort4*>(xn + base + j0) = xb;
    }
}

// ---------------- K2: nearest-neighbor sim row-max via MFMA ----------------
// block = 256 threads = 4 waves; each wave owns 16 rows (one 16-row m-band).
// A fragments (16 rows x K=512) resident in 64 VGPRs; 4 s-subtiles per iter
// with independent accumulators (4-way MFMA ILP); s-range split 4-way across
// blocks (grid 1024 -> 16 waves/CU) with partial-max + reduce pass.
__global__ __launch_bounds__(256, 4) void k2_nn(const unsigned short* __restrict__ xn,
                                                float* __restrict__ partial) {
    const int wave = threadIdx.x >> 6;
    const int lane = threadIdx.x & 63;
    const int bid = blockIdx.x;
    const int sp = bid & (NSPLIT - 1);
    const int tile = (bid >> 2) & 31;     // 32 tiles of 64 rows per batch
    const int b = bid >> 7;               // 8 batches
    const int m0 = tile * 64 + wave * 16; // batch-local row base for this wave
    const size_t bbase = (size_t)b * TT * DD;

    const int r15 = lane & 15;
    const int kgrp = lane >> 4;  // 0..3

    // A fragments: A[m][k], m = lane&15, k = kk*32 + kgrp*8 + j
    bf16x8 a[16];
    const unsigned short* arow = xn + bbase + (size_t)(m0 + r15) * DD + kgrp * 8;
#pragma unroll
    for (int kk = 0; kk < 16; ++kk)
        a[kk] = *reinterpret_cast<const bf16x8*>(arow + kk * 32);

    float rmax[4] = {-2.f, -2.f, -2.f, -2.f};

    const int s_begin = sp * SCHUNK;
    for (int s0 = s_begin; s0 < s_begin + SCHUNK; s0 += 64) {
        const unsigned short* brow = xn + bbase + (size_t)(s0 + r15) * DD + kgrp * 8;
        f32x4 acc0 = {0.f, 0.f, 0.f, 0.f};
        f32x4 acc1 = {0.f, 0.f, 0.f, 0.f};
        f32x4 acc2 = {0.f, 0.f, 0.f, 0.f};
        f32x4 acc3 = {0.f, 0.f, 0.f, 0.f};
#pragma unroll
        for (int kk = 0; kk < 16; ++kk) {
            bf16x8 b0 = *reinterpret_cast<const bf16x8*>(brow + kk * 32);
            bf16x8 b1 = *reinterpret_cast<const bf16x8*>(brow + 16 * DD + kk * 32);
            bf16x8 b2 = *reinterpret_cast<const bf16x8*>(brow + 32 * DD + kk * 32);
            bf16x8 b3 = *reinterpret_cast<const bf16x8*>(brow + 48 * DD + kk * 32);
            acc0 = __builtin_amdgcn_mfma_f32_16x16x32_bf16(a[kk], b0, acc0, 0, 0, 0);
            acc1 = __builtin_amdgcn_mfma_f32_16x16x32_bf16(a[kk], b1, acc1, 0, 0, 0);
            acc2 = __builtin_amdgcn_mfma_f32_16x16x32_bf16(a[kk], b2, acc2, 0, 0, 0);
            acc3 = __builtin_amdgcn_mfma_f32_16x16x32_bf16(a[kk], b3, acc3, 0, 0, 0);
        }
        // D layout: col = lane&15, row = (lane>>4)*4 + r  [m89-verified]
#define MAXUP(ACC, ST)                                                     \
        do {                                                               \
            if (s0 + (ST) * 16 == m0) {                                    \
                _Pragma("unroll") for (int r = 0; r < 4; ++r) {            \
                    int i = kgrp * 4 + r;                                  \
                    float v = (i == r15) ? -2.0f : ACC[r];                 \
                    rmax[r] = fmaxf(rmax[r], v);                           \
                }                                                          \
            } else {                                                       \
                _Pragma("unroll") for (int r = 0; r < 4; ++r)              \
                    rmax[r] = fmaxf(rmax[r], ACC[r]);                      \
            }                                                              \
        } while (0)
        MAXUP(acc0, 0);
        MAXUP(acc1, 1);
        MAXUP(acc2, 2);
        MAXUP(acc3, 3);
#undef MAXUP
    }
    // reduce max across the 16 col-lanes (same kgrp group)
#pragma unroll
    for (int r = 0; r < 4; ++r) {
        float v = rmax[r];
        v = fmaxf(v, __shfl_xor(v, 1));
        v = fmaxf(v, __shfl_xor(v, 2));
        v = fmaxf(v, __shfl_xor(v, 4));
        v = fmaxf(v, __shfl_xor(v, 8));
        rmax[r] = v;
    }
    if (r15 == 0) {
#pragma unroll
        for (int r = 0; r < 4; ++r) {
            int row = m0 + kgrp * 4 + r;
            partial[(size_t)(b * TT + row) * NSPLIT + sp] = rmax[r];
        }
    }
}

// ---------------- K2b: reduce partial maxes -> gate_nn ----------------
__global__ __launch_bounds__(256) void k2b_reduce(const float4* __restrict__ partial,
                                                  const float* __restrict__ p_lsn,
                                                  const float* __restrict__ p_lwn,
                                                  float* __restrict__ gate) {
    const int row = blockIdx.x * 256 + threadIdx.x;
    float4 p = partial[row];
    float m = fmaxf(fmaxf(p.x, p.y), fmaxf(p.z, p.w));
    const float sigma_nn = softplus_f(p_lsn[0]);
    const float w_nn = softplus_f(p_lwn[0]);
    float novelty = 0.5f * (1.0f - m);
    gate[row] = 1.0f + w_nn * tanhf(sigma_nn * novelty);
}

// ---------------- K3: scale rows by gate_nn ----------------
__global__ __launch_bounds__(256) void k3_scale(float* __restrict__ out,
                                                const float* __restrict__ gate) {
    size_t i = (size_t)blockIdx.x * blockDim.x + threadIdx.x;  // float4 index
    float4* o4 = reinterpret_cast<float4*>(out);
    int row = (int)(i >> 7);  // 128 float4 per row of 512
    float g = gate[row];
    float4 v = o4[i];
    v.x *= g; v.y *= g; v.z *= g; v.w *= g;
    o4[i] = v;
}

extern "C" void kernel_launch(void* const* d_in, const int* in_sizes, int n_in,
                              void* d_out, int out_size, void* d_ws, size_t ws_size,
                              hipStream_t stream) {
    const float* x = (const float*)d_in[0];
    const float* ema_mean = (const float*)d_in[1];
    const float* ema_sq = (const float*)d_in[2];
    const float* ema_out = (const float*)d_in[3];
    const float* log_tau = (const float*)d_in[4];
    const float* log_beta_up = (const float*)d_in[5];
    const float* log_beta_dn = (const float*)d_in[6];
    const float* log_gamma = (const float*)d_in[7];
    const float* log_sigma_nn = (const float*)d_in[8];
    const float* log_w_nn = (const float*)d_in[9];

    // ws layout: XN bf16 [B*T*D] (16.78 MB) | inv_std f32[512] | ema_n f32[512]
    //            | gate f32[B*T] (64 KB) | partial f32[B*T][NSPLIT] (256 KB)
    char* ws = (char*)d_ws;
    unsigned short* XN = (unsigned short*)ws;
    float* inv_std = (float*)(ws + 16777216);
    float* ema_n = (float*)(ws + 16777216 + 2048);
    float* gate = (float*)(ws + 16777216 + 4096);
    float* partial = (float*)(ws + 16777216 + 4096 + 65536);
    float* out = (float*)d_out;

    hipLaunchKernelGGL(k0_prep, dim3(1), dim3(512), 0, stream, ema_mean, ema_sq, ema_out,
                       inv_std, ema_n);
    hipLaunchKernelGGL(k1_elem, dim3(BB * TT), dim3(64), 0, stream, x, ema_mean, inv_std, ema_n,
                       log_tau, log_beta_up, log_beta_dn, log_gamma, out, XN);
    hipLaunchKernelGGL(k2_nn, dim3(BB * (TT / 64) * NSPLIT), dim3(256), 0, stream, XN, partial);
    hipLaunchKernelGGL(k2b_reduce, dim3(BB * TT / 256), dim3(256), 0, stream,
                       (const float4*)partial, log_sigma_nn, log_w_nn, gate);
    hipLaunchKernelGGL(k3_scale, dim3((BB * TT * DD / 4) / 256), dim3(256), 0, stream, out, gate);
}

// Round 3
// 98.467 us; speedup vs baseline: 3.8809x; 2.9513x over previous
//
#include <hip/hip_runtime.h>
#include <hip/hip_bf16.h>
#include <math.h>

#define BB 8
#define TT 2048
#define DD 512
#define NT (TT / 128)            // 16 col-tiles per row
#define NTRI (NT * (NT + 1) / 2) // 136 upper-triangle tiles

typedef __attribute__((ext_vector_type(8))) short bf16x8;
typedef __attribute__((ext_vector_type(4))) float f32x4;

__device__ inline float softplus_f(float v) { return log1pf(expf(v)); }

// fp32 -> bf16 round-nearest-even on bit pattern
__device__ inline unsigned short f2bf(float f) {
    unsigned int u = __float_as_uint(f);
    unsigned int r = (u + 0x7fffu + ((u >> 16) & 1u)) >> 16;
    return (unsigned short)r;
}

__device__ inline void load_lds16(const void* g, void* l) {
    __builtin_amdgcn_global_load_lds(
        (const __attribute__((address_space(1))) unsigned int*)g,
        (__attribute__((address_space(3))) unsigned int*)l, 16, 0, 0);
}

// ---------------- K0: per-channel prep (inv_std, normalized ema_out) ----------------
__global__ __launch_bounds__(512) void k0_prep(const float* __restrict__ ema_mean,
                                               const float* __restrict__ ema_sq,
                                               const float* __restrict__ ema_out,
                                               float* __restrict__ inv_std,
                                               float* __restrict__ ema_n) {
    __shared__ float red[8];
    int t = threadIdx.x;  // 512 threads, one per channel
    float m = ema_mean[t];
    float v = ema_sq[t] - m * m;
    v = fmaxf(v, 1e-4f);
    inv_std[t] = 1.0f / (sqrtf(v) + 1e-5f);

    float e = ema_out[t];
    float s = e * e;
#pragma unroll
    for (int off = 32; off; off >>= 1) s += __shfl_xor(s, off);
    if ((t & 63) == 0) red[t >> 6] = s;
    __syncthreads();
    if (t == 0) {
        float tot = 0.f;
        for (int i = 0; i < 8; ++i) tot += red[i];
        red[0] = 1.0f / fmaxf(sqrtf(tot), 1e-12f);
    }
    __syncthreads();
    ema_n[t] = e * red[0];
}

// ---------------- K1: per-row elementwise + reductions ----------------
// 256 threads = 4 waves; one wave per row of D=512; 8 elems/thread
__global__ __launch_bounds__(256) void k1_elem(
    const float* __restrict__ x, const float* __restrict__ ema_mean,
    const float* __restrict__ inv_std, const float* __restrict__ ema_n,
    const float* __restrict__ p_log_tau, const float* __restrict__ p_lbu,
    const float* __restrict__ p_lbd, const float* __restrict__ p_lg,
    float* __restrict__ out, unsigned short* __restrict__ xn) {
    const int row = blockIdx.x * 4 + (threadIdx.x >> 6);
    const int lane = threadIdx.x & 63;
    const size_t base = (size_t)row * DD;

    const float tau = expf(p_log_tau[0]);
    const float beta_up = softplus_f(p_lbu[0]);
    const float beta_dn = softplus_f(p_lbd[0]);
    const float gamma = softplus_f(p_lg[0]);

    float xv[8], pg[8];
    float sx2 = 0.f, so2 = 0.f, sod = 0.f;
#pragma unroll
    for (int c = 0; c < 2; ++c) {
        const int j0 = c * 256 + lane * 4;
        float4 xx = *reinterpret_cast<const float4*>(x + base + j0);
        float vv[4] = {xx.x, xx.y, xx.z, xx.w};
#pragma unroll
        for (int q = 0; q < 4; ++q) {
            const int d = j0 + q;
            const int e = c * 4 + q;
            float xf = vv[q];
            xv[e] = xf;
            // gelu (tanh approx)
            float x3 = xf * xf * xf;
            float gl = 0.5f * xf * (1.0f + tanhf(0.7978845608028654f * (xf + 0.044715f * x3)));
            // z-gate
            float z = (xf - ema_mean[d]) * inv_std[d];
            float th = tanhf(gamma * z);
            float up = beta_up * fmaxf(th, 0.0f);
            float dn = beta_dn * fmaxf(-th, 0.0f);
            float gh = fminf(fmaxf(1.0f + up - dn, 0.05f), 8.0f);
            pg[e] = gl * gh;
            sx2 += xf * xf;
            so2 += gl * gl;
            sod += gl * ema_n[d];
        }
    }
#pragma unroll
    for (int off = 32; off; off >>= 1) {
        sx2 += __shfl_xor(sx2, off);
        so2 += __shfl_xor(so2, off);
        sod += __shfl_xor(sod, off);
    }
    const float inv_xnorm = 1.0f / fmaxf(sqrtf(sx2), 1e-12f);
    float cosv = sod / fmaxf(sqrtf(so2), 1e-12f);
    cosv = fminf(fmaxf(cosv, -1.0f), 1.0f);
    const float gcos = expf(-tau * cosv);

#pragma unroll
    for (int c = 0; c < 2; ++c) {
        const int j0 = c * 256 + lane * 4;
        float4 ov;
        ov.x = pg[c * 4 + 0] * gcos;
        ov.y = pg[c * 4 + 1] * gcos;
        ov.z = pg[c * 4 + 2] * gcos;
        ov.w = pg[c * 4 + 3] * gcos;
        *reinterpret_cast<float4*>(out + base + j0) = ov;
        ushort4 xb;
        xb.x = f2bf(xv[c * 4 + 0] * inv_xnorm);
        xb.y = f2bf(xv[c * 4 + 1] * inv_xnorm);
        xb.z = f2bf(xv[c * 4 + 2] * inv_xnorm);
        xb.w = f2bf(xv[c * 4 + 3] * inv_xnorm);
        *reinterpret_cast<ushort4*>(xn + base + j0) = xb;
    }
}

// ---------------- K2: sim row/col max via MFMA, m97 128x128 LDS structure ----------------
// 256 threads = 4 waves (2x2). Upper-triangle tiles only (sim symmetric):
// block computes C-tile (tm,tn), tm<=tn; emits row-max -> partial[...][tn]
// and (tm!=tn) col-max -> partial[...][tm].
// LDS tiles XOR-swizzled via pre-swizzled global source (linear gload_lds dest).
__global__ __launch_bounds__(256) void k2_nn(const unsigned short* __restrict__ xn,
                                             float* __restrict__ partial) {
    __shared__ short As[128 * 64];
    __shared__ short Bs[128 * 64];
    __shared__ float rbuf[2][64][2];
    __shared__ float cbuf[2][64][2];

    const int tid = threadIdx.x;
    const int wave = tid >> 6;
    const int lane = tid & 63;
    const int r15 = lane & 15;
    const int kgrp = lane >> 4;
    const int wr = wave >> 1, wc = wave & 1;

    const int bid = blockIdx.x;
    const int b = bid / NTRI;
    int t = bid % NTRI;
    int tm = 0;
    while (t >= NT - tm) { t -= NT - tm; ++tm; }
    const int tn = tm + t;

    const size_t bbase = (size_t)b * TT * DD;
    const unsigned short* Ag = xn + bbase + (size_t)tm * 128 * DD;
    const unsigned short* Bg = xn + bbase + (size_t)tn * 128 * DD;

    f32x4 acc[4][4];
#pragma unroll
    for (int i = 0; i < 4; ++i)
#pragma unroll
        for (int j = 0; j < 4; ++j) acc[i][j] = (f32x4){0.f, 0.f, 0.f, 0.f};

    // staging geometry: linear LDS byte o = chunk*1024 + lane*16, chunk = q*4+wave
    // row = o>>7 (8 lanes per 128B row); source pre-swizzled: p = o ^ ((row&7)<<4)
    const int swz_lo[1] = {0};  // (silence unused warnings pattern-free)
    for (int ks = 0; ks < DD; ks += 64) {
        __syncthreads();  // previous compute finished before overwrite
#pragma unroll
        for (int q = 0; q < 4; ++q) {
            const int chunk = q * 4 + wave;
            const int o = chunk * 1024 + lane * 16;
            const int row = o >> 7;
            const int p = o ^ ((row & 7) << 4);
            const int col = (p & 127) >> 1;  // element col within BK=64
            load_lds16(Ag + (size_t)row * DD + ks + col, (char*)As + chunk * 1024);
            load_lds16(Bg + (size_t)row * DD + ks + col, (char*)Bs + chunk * 1024);
        }
        __syncthreads();  // compiler drains vmcnt before barrier -> tiles ready
#pragma unroll
        for (int kk = 0; kk < 2; ++kk) {
            bf16x8 a[4], bb[4];
#pragma unroll
            for (int mi = 0; mi < 4; ++mi) {
                const int row = wr * 64 + mi * 16 + r15;
                const int off = row * 128 + ((kk * 64 + kgrp * 16) ^ ((row & 7) << 4));
                a[mi] = *(const bf16x8*)((const char*)As + off);
            }
#pragma unroll
            for (int ni = 0; ni < 4; ++ni) {
                const int row = wc * 64 + ni * 16 + r15;
                const int off = row * 128 + ((kk * 64 + kgrp * 16) ^ ((row & 7) << 4));
                bb[ni] = *(const bf16x8*)((const char*)Bs + off);
            }
#pragma unroll
            for (int mi = 0; mi < 4; ++mi)
#pragma unroll
                for (int ni = 0; ni < 4; ++ni)
                    acc[mi][ni] = __builtin_amdgcn_mfma_f32_16x16x32_bf16(a[mi], bb[ni],
                                                                          acc[mi][ni], 0, 0, 0);
        }
    }
    (void)swz_lo;

    // ---- epilogue: row-max and col-max ----
    // D layout: col = r15, row = kgrp*4 + r (within 16x16 fragment)
    const bool diag = (tm == tn);
#pragma unroll
    for (int mi = 0; mi < 4; ++mi) {
#pragma unroll
        for (int r = 0; r < 4; ++r) {
            float v = -2.0f;
            const int ml = wr * 64 + mi * 16 + kgrp * 4 + r;
#pragma unroll
            for (int ni = 0; ni < 4; ++ni) {
                float e = acc[mi][ni][r];
                if (diag && ml == wc * 64 + ni * 16 + r15) e = -2.0f;
                v = fmaxf(v, e);
            }
            v = fmaxf(v, __shfl_xor(v, 1));
            v = fmaxf(v, __shfl_xor(v, 2));
            v = fmaxf(v, __shfl_xor(v, 4));
            v = fmaxf(v, __shfl_xor(v, 8));
            if (r15 == 0) rbuf[wr][mi * 16 + kgrp * 4 + r][wc] = v;
        }
    }
    if (!diag) {
#pragma unroll
        for (int ni = 0; ni < 4; ++ni) {
            float v = -2.0f;
#pragma unroll
            for (int mi = 0; mi < 4; ++mi)
#pragma unroll
                for (int r = 0; r < 4; ++r) v = fmaxf(v, acc[mi][ni][r]);
            v = fmaxf(v, __shfl_xor(v, 16));
            v = fmaxf(v, __shfl_xor(v, 32));
            if (kgrp == 0) cbuf[wc][ni * 16 + r15][wr] = v;
        }
    }
    __syncthreads();
    if (tid < 128) {
        const int rl = tid;
        const float v = fmaxf(rbuf[rl >> 6][rl & 63][0], rbuf[rl >> 6][rl & 63][1]);
        partial[((size_t)b * TT + tm * 128 + rl) * NT + tn] = v;
    } else if (!diag) {
        const int cl = tid - 128;
        const float v = fmaxf(cbuf[cl >> 6][cl & 63][0], cbuf[cl >> 6][cl & 63][1]);
        partial[((size_t)b * TT + tn * 128 + cl) * NT + tm] = v;
    }
}

// ---------------- K3: reduce partial maxes + scale rows ----------------
// 256 threads = 4 waves; one wave per row
__global__ __launch_bounds__(256) void k3_scale(float* __restrict__ out,
                                                const float* __restrict__ partial,
                                                const float* __restrict__ p_lsn,
                                                const float* __restrict__ p_lwn) {
    const int row = blockIdx.x * 4 + (threadIdx.x >> 6);
    const int lane = threadIdx.x & 63;
    const float sigma_nn = softplus_f(p_lsn[0]);
    const float w_nn = softplus_f(p_lwn[0]);

    float p = partial[(size_t)row * NT + (lane & 15)];
    p = fmaxf(p, __shfl_xor(p, 1));
    p = fmaxf(p, __shfl_xor(p, 2));
    p = fmaxf(p, __shfl_xor(p, 4));
    p = fmaxf(p, __shfl_xor(p, 8));
    const float g = 1.0f + w_nn * tanhf(sigma_nn * 0.5f * (1.0f - p));

    float4* o4 = reinterpret_cast<float4*>(out + (size_t)row * DD);
    float4 u = o4[lane];
    u.x *= g; u.y *= g; u.z *= g; u.w *= g;
    o4[lane] = u;
    float4 u2 = o4[lane + 64];
    u2.x *= g; u2.y *= g; u2.z *= g; u2.w *= g;
    o4[lane + 64] = u2;
}

extern "C" void kernel_launch(void* const* d_in, const int* in_sizes, int n_in,
                              void* d_out, int out_size, void* d_ws, size_t ws_size,
                              hipStream_t stream) {
    const float* x = (const float*)d_in[0];
    const float* ema_mean = (const float*)d_in[1];
    const float* ema_sq = (const float*)d_in[2];
    const float* ema_out = (const float*)d_in[3];
    const float* log_tau = (const float*)d_in[4];
    const float* log_beta_up = (const float*)d_in[5];
    const float* log_beta_dn = (const float*)d_in[6];
    const float* log_gamma = (const float*)d_in[7];
    const float* log_sigma_nn = (const float*)d_in[8];
    const float* log_w_nn = (const float*)d_in[9];

    // ws layout: XN bf16 [B*T*D] (16.78 MB) | inv_std f32[512] | ema_n f32[512]
    //            | partial f32[B*T][NT] (1 MB)
    char* ws = (char*)d_ws;
    unsigned short* XN = (unsigned short*)ws;
    float* inv_std = (float*)(ws + 16777216);
    float* ema_n = (float*)(ws + 16777216 + 2048);
    float* partial = (float*)(ws + 16777216 + 4096);
    float* out = (float*)d_out;

    hipLaunchKernelGGL(k0_prep, dim3(1), dim3(512), 0, stream, ema_mean, ema_sq, ema_out,
                       inv_std, ema_n);
    hipLaunchKernelGGL(k1_elem, dim3(BB * TT / 4), dim3(256), 0, stream, x, ema_mean, inv_std,
                       ema_n, log_tau, log_beta_up, log_beta_dn, log_gamma, out, XN);
    hipLaunchKernelGGL(k2_nn, dim3(BB * NTRI), dim3(256), 0, stream, XN, partial);
    hipLaunchKernelGGL(k3_scale, dim3(BB * TT / 4), dim3(256), 0, stream, out, partial,
                       log_sigma_nn, log_w_nn);
}

// Round 4
// 75.662 us; speedup vs baseline: 5.0506x; 1.3014x over previous
//
#include <hip/hip_runtime.h>
#include <hip/hip_bf16.h>
#include <math.h>

#define BB 8
#define TT 2048
#define DD 512
#define NT (TT / 128)            // 16 col-tiles per row
#define NTRI (NT * (NT + 1) / 2) // 136 upper-triangle tiles

typedef __attribute__((ext_vector_type(8))) short bf16x8;
typedef __attribute__((ext_vector_type(4))) float f32x4;

__device__ inline float softplus_f(float v) { return log1pf(expf(v)); }

// fast tanh: 1 - 2/(exp2(2*log2e*y)+1); v_exp_f32 + v_rcp_f32, ~1e-6 rel err
__device__ inline float tanh_fast(float y) {
    float e = __builtin_amdgcn_exp2f(y * 2.8853900817779268f);
    return 1.0f - 2.0f * __builtin_amdgcn_rcpf(e + 1.0f);
}
__device__ inline float exp_fast(float y) {
    return __builtin_amdgcn_exp2f(y * 1.4426950408889634f);
}

// fp32 -> bf16 round-nearest-even on bit pattern
__device__ inline unsigned short f2bf(float f) {
    unsigned int u = __float_as_uint(f);
    unsigned int r = (u + 0x7fffu + ((u >> 16) & 1u)) >> 16;
    return (unsigned short)r;
}

__device__ inline void load_lds16(const void* g, void* l) {
    __builtin_amdgcn_global_load_lds(
        (const __attribute__((address_space(1))) unsigned int*)g,
        (__attribute__((address_space(3))) unsigned int*)l, 16, 0, 0);
}

// ---------------- K0: per-channel prep (inv_std, normalized ema_out) ----------------
__global__ __launch_bounds__(512) void k0_prep(const float* __restrict__ ema_mean,
                                               const float* __restrict__ ema_sq,
                                               const float* __restrict__ ema_out,
                                               float* __restrict__ inv_std,
                                               float* __restrict__ ema_n) {
    __shared__ float red[8];
    int t = threadIdx.x;  // 512 threads, one per channel
    float m = ema_mean[t];
    float v = ema_sq[t] - m * m;
    v = fmaxf(v, 1e-4f);
    inv_std[t] = 1.0f / (sqrtf(v) + 1e-5f);

    float e = ema_out[t];
    float s = e * e;
#pragma unroll
    for (int off = 32; off; off >>= 1) s += __shfl_xor(s, off);
    if ((t & 63) == 0) red[t >> 6] = s;
    __syncthreads();
    if (t == 0) {
        float tot = 0.f;
        for (int i = 0; i < 8; ++i) tot += red[i];
        red[0] = 1.0f / fmaxf(sqrtf(tot), 1e-12f);
    }
    __syncthreads();
    ema_n[t] = e * red[0];
}

// ---------------- K1: per-row elementwise + reductions ----------------
// 256 threads = 4 waves; one wave per row of D=512; 8 elems/thread
__global__ __launch_bounds__(256) void k1_elem(
    const float* __restrict__ x, const float* __restrict__ ema_mean,
    const float* __restrict__ inv_std, const float* __restrict__ ema_n,
    const float* __restrict__ p_log_tau, const float* __restrict__ p_lbu,
    const float* __restrict__ p_lbd, const float* __restrict__ p_lg,
    float* __restrict__ out, unsigned short* __restrict__ xn) {
    const int row = blockIdx.x * 4 + (threadIdx.x >> 6);
    const int lane = threadIdx.x & 63;
    const size_t base = (size_t)row * DD;

    const float tau = expf(p_log_tau[0]);
    const float beta_up = softplus_f(p_lbu[0]);
    const float beta_dn = softplus_f(p_lbd[0]);
    const float gamma = softplus_f(p_lg[0]);

    float xv[8], pg[8];
    float sx2 = 0.f, so2 = 0.f, sod = 0.f;
#pragma unroll
    for (int c = 0; c < 2; ++c) {
        const int j0 = c * 256 + lane * 4;
        float4 xx = *reinterpret_cast<const float4*>(x + base + j0);
        float vv[4] = {xx.x, xx.y, xx.z, xx.w};
#pragma unroll
        for (int q = 0; q < 4; ++q) {
            const int d = j0 + q;
            const int e = c * 4 + q;
            float xf = vv[q];
            xv[e] = xf;
            // gelu (tanh approx)
            float x3 = xf * xf * xf;
            float gl = 0.5f * xf * (1.0f + tanh_fast(0.7978845608028654f * (xf + 0.044715f * x3)));
            // z-gate
            float z = (xf - ema_mean[d]) * inv_std[d];
            float th = tanh_fast(gamma * z);
            float up = beta_up * fmaxf(th, 0.0f);
            float dn = beta_dn * fmaxf(-th, 0.0f);
            float gh = fminf(fmaxf(1.0f + up - dn, 0.05f), 8.0f);
            pg[e] = gl * gh;
            sx2 += xf * xf;
            so2 += gl * gl;
            sod += gl * ema_n[d];
        }
    }
#pragma unroll
    for (int off = 32; off; off >>= 1) {
        sx2 += __shfl_xor(sx2, off);
        so2 += __shfl_xor(so2, off);
        sod += __shfl_xor(sod, off);
    }
    const float inv_xnorm = 1.0f / fmaxf(sqrtf(sx2), 1e-12f);
    float cosv = sod / fmaxf(sqrtf(so2), 1e-12f);
    cosv = fminf(fmaxf(cosv, -1.0f), 1.0f);
    const float gcos = exp_fast(-tau * cosv);

#pragma unroll
    for (int c = 0; c < 2; ++c) {
        const int j0 = c * 256 + lane * 4;
        float4 ov;
        ov.x = pg[c * 4 + 0] * gcos;
        ov.y = pg[c * 4 + 1] * gcos;
        ov.z = pg[c * 4 + 2] * gcos;
        ov.w = pg[c * 4 + 3] * gcos;
        *reinterpret_cast<float4*>(out + base + j0) = ov;
        ushort4 xb;
        xb.x = f2bf(xv[c * 4 + 0] * inv_xnorm);
        xb.y = f2bf(xv[c * 4 + 1] * inv_xnorm);
        xb.z = f2bf(xv[c * 4 + 2] * inv_xnorm);
        xb.w = f2bf(xv[c * 4 + 3] * inv_xnorm);
        *reinterpret_cast<ushort4*>(xn + base + j0) = xb;
    }
}

// ---------------- K2: sim row/col max via MFMA ----------------
// 256 threads = 4 waves (2x2), 128x128 C-tile, BK=64, 2-phase double-buffered
// LDS (stage next || compute cur, one vmcnt(0)+barrier per K-step).
// Upper-triangle tiles only (sim symmetric); XCD swizzle: b = bid%8 so each
// batch's 2 MB XN panel stays in one XCD's 4 MB L2.
// LDS tiles XOR-swizzled via pre-swizzled global source (linear gload_lds dest).
__global__ __launch_bounds__(256) void k2_nn(const unsigned short* __restrict__ xn,
                                             float* __restrict__ partial) {
    __shared__ short As[2][128 * 64];
    __shared__ short Bs[2][128 * 64];
    __shared__ float rbuf[2][64][2];
    __shared__ float cbuf[2][64][2];

    const int tid = threadIdx.x;
    const int wave = tid >> 6;
    const int lane = tid & 63;
    const int r15 = lane & 15;
    const int kgrp = lane >> 4;
    const int wr = wave >> 1, wc = wave & 1;

    const int bid = blockIdx.x;
    const int b = bid & 7;   // XCD swizzle: batch pinned to one XCD's L2
    int t = bid >> 3;        // 0..NTRI-1
    int tm = 0;
    while (t >= NT - tm) { t -= NT - tm; ++tm; }
    const int tn = tm + t;

    const size_t bbase = (size_t)b * TT * DD;
    const unsigned short* Ag = xn + bbase + (size_t)tm * 128 * DD;
    const unsigned short* Bg = xn + bbase + (size_t)tn * 128 * DD;

    f32x4 acc[4][4];
#pragma unroll
    for (int i = 0; i < 4; ++i)
#pragma unroll
        for (int j = 0; j < 4; ++j) acc[i][j] = (f32x4){0.f, 0.f, 0.f, 0.f};

    // staging: linear LDS byte o = chunk*1024 + lane*16, chunk = q*4+wave;
    // row = o>>7; source pre-swizzled p = o ^ ((row&7)<<4) (rule 21)
#define STAGE(BUF, KS)                                                        \
    do {                                                                      \
        _Pragma("unroll") for (int q = 0; q < 4; ++q) {                       \
            const int chunk = q * 4 + wave;                                   \
            const int o = chunk * 1024 + lane * 16;                           \
            const int row = o >> 7;                                           \
            const int p = o ^ ((row & 7) << 4);                               \
            const int col = (p & 127) >> 1;                                   \
            load_lds16(Ag + (size_t)row * DD + (KS) + col,                    \
                       (char*)As[BUF] + chunk * 1024);                        \
            load_lds16(Bg + (size_t)row * DD + (KS) + col,                    \
                       (char*)Bs[BUF] + chunk * 1024);                        \
        }                                                                     \
    } while (0)

#define COMPUTE(BUF)                                                          \
    do {                                                                      \
        _Pragma("unroll") for (int kk = 0; kk < 2; ++kk) {                    \
            bf16x8 a[4], bb[4];                                               \
            _Pragma("unroll") for (int mi = 0; mi < 4; ++mi) {                \
                const int row = wr * 64 + mi * 16 + r15;                      \
                const int off =                                               \
                    row * 128 + ((kk * 64 + kgrp * 16) ^ ((row & 7) << 4));   \
                a[mi] = *(const bf16x8*)((const char*)As[BUF] + off);         \
            }                                                                 \
            _Pragma("unroll") for (int ni = 0; ni < 4; ++ni) {                \
                const int row = wc * 64 + ni * 16 + r15;                      \
                const int off =                                               \
                    row * 128 + ((kk * 64 + kgrp * 16) ^ ((row & 7) << 4));   \
                bb[ni] = *(const bf16x8*)((const char*)Bs[BUF] + off);        \
            }                                                                 \
            _Pragma("unroll") for (int mi = 0; mi < 4; ++mi)                  \
                _Pragma("unroll") for (int ni = 0; ni < 4; ++ni)              \
                    acc[mi][ni] = __builtin_amdgcn_mfma_f32_16x16x32_bf16(    \
                        a[mi], bb[ni], acc[mi][ni], 0, 0, 0);                 \
        }                                                                     \
    } while (0)

    STAGE(0, 0);
    __syncthreads();  // drains vmcnt(0): buf0 ready
    int cur = 0;
#pragma unroll
    for (int ks = 64; ks < DD; ks += 64) {
        if (cur == 0) {
            STAGE(1, ks);   // issue next-tile loads (overlap with compute)
            COMPUTE(0);
        } else {
            STAGE(0, ks);
            COMPUTE(1);
        }
        __syncthreads();    // vmcnt(0)+lgkmcnt(0)+barrier: next buf ready
        cur ^= 1;
    }
    COMPUTE(cur);
#undef STAGE
#undef COMPUTE

    // ---- epilogue: row-max and col-max ----
    // D layout: col = r15, row = kgrp*4 + r (within 16x16 fragment)
    const bool diag = (tm == tn);
#pragma unroll
    for (int mi = 0; mi < 4; ++mi) {
#pragma unroll
        for (int r = 0; r < 4; ++r) {
            float v = -2.0f;
            const int ml = wr * 64 + mi * 16 + kgrp * 4 + r;
#pragma unroll
            for (int ni = 0; ni < 4; ++ni) {
                float e = acc[mi][ni][r];
                if (diag && ml == wc * 64 + ni * 16 + r15) e = -2.0f;
                v = fmaxf(v, e);
            }
            v = fmaxf(v, __shfl_xor(v, 1));
            v = fmaxf(v, __shfl_xor(v, 2));
            v = fmaxf(v, __shfl_xor(v, 4));
            v = fmaxf(v, __shfl_xor(v, 8));
            if (r15 == 0) rbuf[wr][mi * 16 + kgrp * 4 + r][wc] = v;
        }
    }
    if (!diag) {
#pragma unroll
        for (int ni = 0; ni < 4; ++ni) {
            float v = -2.0f;
#pragma unroll
            for (int mi = 0; mi < 4; ++mi)
#pragma unroll
                for (int r = 0; r < 4; ++r) v = fmaxf(v, acc[mi][ni][r]);
            v = fmaxf(v, __shfl_xor(v, 16));
            v = fmaxf(v, __shfl_xor(v, 32));
            if (kgrp == 0) cbuf[wc][ni * 16 + r15][wr] = v;
        }
    }
    __syncthreads();
    if (tid < 128) {
        const int rl = tid;
        const float v = fmaxf(rbuf[rl >> 6][rl & 63][0], rbuf[rl >> 6][rl & 63][1]);
        partial[((size_t)b * TT + tm * 128 + rl) * NT + tn] = v;
    } else if (!diag) {
        const int cl = tid - 128;
        const float v = fmaxf(cbuf[cl >> 6][cl & 63][0], cbuf[cl >> 6][cl & 63][1]);
        partial[((size_t)b * TT + tn * 128 + cl) * NT + tm] = v;
    }
}

// ---------------- K3: reduce partial maxes + scale rows ----------------
// 256 threads = 4 waves; one wave per row
__global__ __launch_bounds__(256) void k3_scale(float* __restrict__ out,
                                                const float* __restrict__ partial,
                                                const float* __restrict__ p_lsn,
                                                const float* __restrict__ p_lwn) {
    const int row = blockIdx.x * 4 + (threadIdx.x >> 6);
    const int lane = threadIdx.x & 63;
    const float sigma_nn = softplus_f(p_lsn[0]);
    const float w_nn = softplus_f(p_lwn[0]);

    float p = partial[(size_t)row * NT + (lane & 15)];
    p = fmaxf(p, __shfl_xor(p, 1));
    p = fmaxf(p, __shfl_xor(p, 2));
    p = fmaxf(p, __shfl_xor(p, 4));
    p = fmaxf(p, __shfl_xor(p, 8));
    const float g = 1.0f + w_nn * tanh_fast(sigma_nn * 0.5f * (1.0f - p));

    float4* o4 = reinterpret_cast<float4*>(out + (size_t)row * DD);
    float4 u = o4[lane];
    u.x *= g; u.y *= g; u.z *= g; u.w *= g;
    o4[lane] = u;
    float4 u2 = o4[lane + 64];
    u2.x *= g; u2.y *= g; u2.z *= g; u2.w *= g;
    o4[lane + 64] = u2;
}

extern "C" void kernel_launch(void* const* d_in, const int* in_sizes, int n_in,
                              void* d_out, int out_size, void* d_ws, size_t ws_size,
                              hipStream_t stream) {
    const float* x = (const float*)d_in[0];
    const float* ema_mean = (const float*)d_in[1];
    const float* ema_sq = (const float*)d_in[2];
    const float* ema_out = (const float*)d_in[3];
    const float* log_tau = (const float*)d_in[4];
    const float* log_beta_up = (const float*)d_in[5];
    const float* log_beta_dn = (const float*)d_in[6];
    const float* log_gamma = (const float*)d_in[7];
    const float* log_sigma_nn = (const float*)d_in[8];
    const float* log_w_nn = (const float*)d_in[9];

    // ws layout: XN bf16 [B*T*D] (16.78 MB) | inv_std f32[512] | ema_n f32[512]
    //            | partial f32[B*T][NT] (1 MB)
    char* ws = (char*)d_ws;
    unsigned short* XN = (unsigned short*)ws;
    float* inv_std = (float*)(ws + 16777216);
    float* ema_n = (float*)(ws + 16777216 + 2048);
    float* partial = (float*)(ws + 16777216 + 4096);
    float* out = (float*)d_out;

    hipLaunchKernelGGL(k0_prep, dim3(1), dim3(512), 0, stream, ema_mean, ema_sq, ema_out,
                       inv_std, ema_n);
    hipLaunchKernelGGL(k1_elem, dim3(BB * TT / 4), dim3(256), 0, stream, x, ema_mean, inv_std,
                       ema_n, log_tau, log_beta_up, log_beta_dn, log_gamma, out, XN);
    hipLaunchKernelGGL(k2_nn, dim3(BB * NTRI), dim3(256), 0, stream, XN, partial);
    hipLaunchKernelGGL(k3_scale, dim3(BB * TT / 4), dim3(256), 0, stream, out, partial,
                       log_sigma_nn, log_w_nn);
}

// Round 5
// 73.949 us; speedup vs baseline: 5.1676x; 1.0232x over previous
//
#include <hip/hip_runtime.h>
#include <hip/hip_bf16.h>
#include <math.h>

#define BB 8
#define TT 2048
#define DD 512
#define NT (TT / 128)            // 16 col-tiles per row
#define NTRI (NT * (NT + 1) / 2) // 136 upper-triangle tiles

typedef __attribute__((ext_vector_type(8))) short bf16x8;
typedef __attribute__((ext_vector_type(4))) float f32x4;

__device__ inline float softplus_f(float v) { return log1pf(expf(v)); }

// fast tanh: 1 - 2/(exp2(2*log2e*y)+1); v_exp_f32 + v_rcp_f32, ~1e-6 rel err
__device__ inline float tanh_fast(float y) {
    float e = __builtin_amdgcn_exp2f(y * 2.8853900817779268f);
    return 1.0f - 2.0f * __builtin_amdgcn_rcpf(e + 1.0f);
}
__device__ inline float exp_fast(float y) {
    return __builtin_amdgcn_exp2f(y * 1.4426950408889634f);
}

// fp32 -> bf16 round-nearest-even on bit pattern
__device__ inline unsigned short f2bf(float f) {
    unsigned int u = __float_as_uint(f);
    unsigned int r = (u + 0x7fffu + ((u >> 16) & 1u)) >> 16;
    return (unsigned short)r;
}
__device__ inline float bf2f(unsigned short h) {
    unsigned int u = ((unsigned int)h) << 16;
    return __uint_as_float(u);
}

__device__ inline void load_lds16(const void* g, void* l) {
    __builtin_amdgcn_global_load_lds(
        (const __attribute__((address_space(1))) unsigned int*)g,
        (__attribute__((address_space(3))) unsigned int*)l, 16, 0, 0);
}

// ---------------- K1: fused prep + per-row elementwise + reductions ----------------
// 256 threads = 4 waves; one wave per row of D=512; 8 elems/thread.
// Computes inv_std inline from ema_mean/ema_sq; per-wave reduce of ||ema_out||.
// Writes XN (normalized x, bf16) and PO (gelu*gate_hist*gate_cos, bf16).
__global__ __launch_bounds__(256) void k1_elem(
    const float* __restrict__ x, const float* __restrict__ ema_mean,
    const float* __restrict__ ema_sq, const float* __restrict__ ema_out,
    const float* __restrict__ p_log_tau, const float* __restrict__ p_lbu,
    const float* __restrict__ p_lbd, const float* __restrict__ p_lg,
    unsigned short* __restrict__ xn, unsigned short* __restrict__ po) {
    const int row = blockIdx.x * 4 + (threadIdx.x >> 6);
    const int lane = threadIdx.x & 63;
    const size_t base = (size_t)row * DD;

    const float tau = expf(p_log_tau[0]);
    const float beta_up = softplus_f(p_lbu[0]);
    const float beta_dn = softplus_f(p_lbd[0]);
    const float gamma = softplus_f(p_lg[0]);

    float xv[8], pg[8];
    float sx2 = 0.f, so2 = 0.f, sod = 0.f, se2 = 0.f;
#pragma unroll
    for (int c = 0; c < 2; ++c) {
        const int j0 = c * 256 + lane * 4;
        float4 xx = *reinterpret_cast<const float4*>(x + base + j0);
        float4 mm = *reinterpret_cast<const float4*>(ema_mean + j0);
        float4 qq = *reinterpret_cast<const float4*>(ema_sq + j0);
        float4 eo = *reinterpret_cast<const float4*>(ema_out + j0);
        float vv[4] = {xx.x, xx.y, xx.z, xx.w};
        float vm[4] = {mm.x, mm.y, mm.z, mm.w};
        float vq[4] = {qq.x, qq.y, qq.z, qq.w};
        float ve[4] = {eo.x, eo.y, eo.z, eo.w};
#pragma unroll
        for (int q = 0; q < 4; ++q) {
            const int e = c * 4 + q;
            float xf = vv[q];
            xv[e] = xf;
            // gelu (tanh approx)
            float x3 = xf * xf * xf;
            float gl = 0.5f * xf * (1.0f + tanh_fast(0.7978845608028654f * (xf + 0.044715f * x3)));
            // z-gate (inv_std inline)
            float var = fmaxf(vq[q] - vm[q] * vm[q], 1e-4f);
            float istd = __builtin_amdgcn_rcpf(sqrtf(var) + 1e-5f);
            float z = (xf - vm[q]) * istd;
            float th = tanh_fast(gamma * z);
            float up = beta_up * fmaxf(th, 0.0f);
            float dn = beta_dn * fmaxf(-th, 0.0f);
            float gh = fminf(fmaxf(1.0f + up - dn, 0.05f), 8.0f);
            pg[e] = gl * gh;
            sx2 += xf * xf;
            so2 += gl * gl;
            sod += gl * ve[q];
            se2 += ve[q] * ve[q];
        }
    }
#pragma unroll
    for (int off = 32; off; off >>= 1) {
        sx2 += __shfl_xor(sx2, off);
        so2 += __shfl_xor(so2, off);
        sod += __shfl_xor(sod, off);
        se2 += __shfl_xor(se2, off);
    }
    const float inv_xnorm = __builtin_amdgcn_rcpf(fmaxf(sqrtf(sx2), 1e-12f));
    const float inv_en = __builtin_amdgcn_rcpf(fmaxf(sqrtf(se2), 1e-12f));
    float cosv = sod * inv_en * __builtin_amdgcn_rcpf(fmaxf(sqrtf(so2), 1e-12f));
    cosv = fminf(fmaxf(cosv, -1.0f), 1.0f);
    const float gcos = exp_fast(-tau * cosv);

#pragma unroll
    for (int c = 0; c < 2; ++c) {
        const int j0 = c * 256 + lane * 4;
        ushort4 pb;
        pb.x = f2bf(pg[c * 4 + 0] * gcos);
        pb.y = f2bf(pg[c * 4 + 1] * gcos);
        pb.z = f2bf(pg[c * 4 + 2] * gcos);
        pb.w = f2bf(pg[c * 4 + 3] * gcos);
        *reinterpret_cast<ushort4*>(po + base + j0) = pb;
        ushort4 xb;
        xb.x = f2bf(xv[c * 4 + 0] * inv_xnorm);
        xb.y = f2bf(xv[c * 4 + 1] * inv_xnorm);
        xb.z = f2bf(xv[c * 4 + 2] * inv_xnorm);
        xb.w = f2bf(xv[c * 4 + 3] * inv_xnorm);
        *reinterpret_cast<ushort4*>(xn + base + j0) = xb;
    }
}

// ---------------- K2: sim row/col max via MFMA ----------------
// 256 threads = 4 waves (2x2), 128x128 C-tile, BK=32, double-buffered LDS
// sized for 4 blocks/CU (34 KB): TLP across blocks + dbuf ILP hide staging.
// LDS layout: super-row packing — two 64B logical rows per 128B LDS row,
// XOR-swizzled: s(row,cb) = (row>>1)*128 + ((64*(row&1)+cb) ^ (((row>>1)&7)<<4)).
// gload_lds dest stays linear; global SOURCE is inverse-swizzled (rule 21).
// Upper-triangle tiles only (sim symmetric); XCD pinning: b = bid&7.
__global__ __launch_bounds__(256, 4) void k2_nn(const unsigned short* __restrict__ xn,
                                                float* __restrict__ partial) {
    __shared__ short As[2][128 * 32];
    __shared__ short Bs[2][128 * 32];
    __shared__ float rbuf[2][64][2];
    __shared__ float cbuf[2][64][2];

    const int tid = threadIdx.x;
    const int wave = tid >> 6;
    const int lane = tid & 63;
    const int r15 = lane & 15;
    const int kgrp = lane >> 4;
    const int wr = wave >> 1, wc = wave & 1;

    const int bid = blockIdx.x;
    const int b = bid & 7;   // XCD pinning: batch -> one XCD's L2
    int t = bid >> 3;        // 0..NTRI-1
    int tm = 0;
    while (t >= NT - tm) { t -= NT - tm; ++tm; }
    const int tn = tm + t;

    const size_t bbase = (size_t)b * TT * DD;
    const unsigned short* Ag = xn + bbase + (size_t)tm * 128 * DD;
    const unsigned short* Bg = xn + bbase + (size_t)tn * 128 * DD;

    f32x4 acc[4][4];
#pragma unroll
    for (int i = 0; i < 4; ++i)
#pragma unroll
        for (int j = 0; j < 4; ++j) acc[i][j] = (f32x4){0.f, 0.f, 0.f, 0.f};

    // STAGE: 8 chunks of 1 KB per array; wave handles chunks {2w, 2w+1}.
    // For linear dest byte o: super=o>>7, w=(o&127)^((super&7)<<4),
    // row=2*super+(w>>6), colbyte=w&63 (16B-aligned since XOR hits bits 4-6).
#define STAGE(BUF, KS)                                                        \
    do {                                                                      \
        _Pragma("unroll") for (int q = 0; q < 2; ++q) {                       \
            const int chunk = wave * 2 + q;                                   \
            const int o = chunk * 1024 + lane * 16;                           \
            const int sup = o >> 7;                                           \
            const int w = (o & 127) ^ ((sup & 7) << 4);                       \
            const int row = sup * 2 + (w >> 6);                               \
            const int cole = (w & 63) >> 1;                                   \
            load_lds16(Ag + (size_t)row * DD + (KS) + cole,                   \
                       (char*)As[BUF] + chunk * 1024);                        \
            load_lds16(Bg + (size_t)row * DD + (KS) + cole,                   \
                       (char*)Bs[BUF] + chunk * 1024);                        \
        }                                                                     \
    } while (0)

    // fragment read: row's 16B at col-block kgrp
#define LADDR(ROW) \
    (((ROW) >> 1) * 128 + ((64 * ((ROW) & 1) + kgrp * 16) ^ ((((ROW) >> 1) & 7) << 4)))

#define COMPUTE(BUF)                                                          \
    do {                                                                      \
        bf16x8 a[4], bb[4];                                                   \
        _Pragma("unroll") for (int mi = 0; mi < 4; ++mi) {                    \
            const int row = wr * 64 + mi * 16 + r15;                          \
            a[mi] = *(const bf16x8*)((const char*)As[BUF] + LADDR(row));      \
        }                                                                     \
        _Pragma("unroll") for (int ni = 0; ni < 4; ++ni) {                    \
            const int row = wc * 64 + ni * 16 + r15;                          \
            bb[ni] = *(const bf16x8*)((const char*)Bs[BUF] + LADDR(row));     \
        }                                                                     \
        _Pragma("unroll") for (int mi = 0; mi < 4; ++mi)                      \
            _Pragma("unroll") for (int ni = 0; ni < 4; ++ni)                  \
                acc[mi][ni] = __builtin_amdgcn_mfma_f32_16x16x32_bf16(        \
                    a[mi], bb[ni], acc[mi][ni], 0, 0, 0);                     \
    } while (0)

    STAGE(0, 0);
    __syncthreads();  // drains vmcnt(0): buf0 ready
    int cur = 0;
#pragma unroll
    for (int ks = 32; ks < DD; ks += 32) {
        if (cur == 0) {
            STAGE(1, ks);   // issue next-subtile loads (overlap with compute)
            COMPUTE(0);
        } else {
            STAGE(0, ks);
            COMPUTE(1);
        }
        __syncthreads();    // vmcnt(0)+lgkmcnt(0)+barrier: next buf ready
        cur ^= 1;
    }
    COMPUTE(cur);
#undef STAGE
#undef COMPUTE
#undef LADDR

    // ---- epilogue: row-max and col-max ----
    // D layout: col = r15, row = kgrp*4 + r (within 16x16 fragment)
    const bool diag = (tm == tn);
#pragma unroll
    for (int mi = 0; mi < 4; ++mi) {
#pragma unroll
        for (int r = 0; r < 4; ++r) {
            float v = -2.0f;
            const int ml = wr * 64 + mi * 16 + kgrp * 4 + r;
#pragma unroll
            for (int ni = 0; ni < 4; ++ni) {
                float e = acc[mi][ni][r];
                if (diag && ml == wc * 64 + ni * 16 + r15) e = -2.0f;
                v = fmaxf(v, e);
            }
            v = fmaxf(v, __shfl_xor(v, 1));
            v = fmaxf(v, __shfl_xor(v, 2));
            v = fmaxf(v, __shfl_xor(v, 4));
            v = fmaxf(v, __shfl_xor(v, 8));
            if (r15 == 0) rbuf[wr][mi * 16 + kgrp * 4 + r][wc] = v;
        }
    }
    if (!diag) {
#pragma unroll
        for (int ni = 0; ni < 4; ++ni) {
            float v = -2.0f;
#pragma unroll
            for (int mi = 0; mi < 4; ++mi)
#pragma unroll
                for (int r = 0; r < 4; ++r) v = fmaxf(v, acc[mi][ni][r]);
            v = fmaxf(v, __shfl_xor(v, 16));
            v = fmaxf(v, __shfl_xor(v, 32));
            if (kgrp == 0) cbuf[wc][ni * 16 + r15][wr] = v;
        }
    }
    __syncthreads();
    if (tid < 128) {
        const int rl = tid;
        const float v = fmaxf(rbuf[rl >> 6][rl & 63][0], rbuf[rl >> 6][rl & 63][1]);
        partial[((size_t)b * TT + tm * 128 + rl) * NT + tn] = v;
    } else if (!diag) {
        const int cl = tid - 128;
        const float v = fmaxf(cbuf[cl >> 6][cl & 63][0], cbuf[cl >> 6][cl & 63][1]);
        partial[((size_t)b * TT + tn * 128 + cl) * NT + tm] = v;
    }
}

// ---------------- K3: reduce partial maxes + gate_nn scale + final write ----------------
// 256 threads = 4 waves; one wave per row; reads bf16 PO, writes f32 out.
__global__ __launch_bounds__(256) void k3_scale(float* __restrict__ out,
                                                const unsigned short* __restrict__ po,
                                                const float* __restrict__ partial,
                                                const float* __restrict__ p_lsn,
                                                const float* __restrict__ p_lwn) {
    const int row = blockIdx.x * 4 + (threadIdx.x >> 6);
    const int lane = threadIdx.x & 63;
    const float sigma_nn = softplus_f(p_lsn[0]);
    const float w_nn = softplus_f(p_lwn[0]);

    float p = partial[(size_t)row * NT + (lane & 15)];
    p = fmaxf(p, __shfl_xor(p, 1));
    p = fmaxf(p, __shfl_xor(p, 2));
    p = fmaxf(p, __shfl_xor(p, 4));
    p = fmaxf(p, __shfl_xor(p, 8));
    const float g = 1.0f + w_nn * tanh_fast(sigma_nn * 0.5f * (1.0f - p));

    const size_t base = (size_t)row * DD + lane * 8;
    ushort4 p0 = *reinterpret_cast<const ushort4*>(po + base);
    ushort4 p1 = *reinterpret_cast<const ushort4*>(po + base + 4);
    float4 o0, o1;
    o0.x = bf2f(p0.x) * g; o0.y = bf2f(p0.y) * g;
    o0.z = bf2f(p0.z) * g; o0.w = bf2f(p0.w) * g;
    o1.x = bf2f(p1.x) * g; o1.y = bf2f(p1.y) * g;
    o1.z = bf2f(p1.z) * g; o1.w = bf2f(p1.w) * g;
    *reinterpret_cast<float4*>(out + base) = o0;
    *reinterpret_cast<float4*>(out + base + 4) = o1;
}

extern "C" void kernel_launch(void* const* d_in, const int* in_sizes, int n_in,
                              void* d_out, int out_size, void* d_ws, size_t ws_size,
                              hipStream_t stream) {
    const float* x = (const float*)d_in[0];
    const float* ema_mean = (const float*)d_in[1];
    const float* ema_sq = (const float*)d_in[2];
    const float* ema_out = (const float*)d_in[3];
    const float* log_tau = (const float*)d_in[4];
    const float* log_beta_up = (const float*)d_in[5];
    const float* log_beta_dn = (const float*)d_in[6];
    const float* log_gamma = (const float*)d_in[7];
    const float* log_sigma_nn = (const float*)d_in[8];
    const float* log_w_nn = (const float*)d_in[9];

    // ws layout: XN bf16 [B*T*D] (16.78 MB) | PO bf16 [B*T*D] (16.78 MB)
    //            | partial f32[B*T][NT] (1 MB)
    char* ws = (char*)d_ws;
    unsigned short* XN = (unsigned short*)ws;
    unsigned short* PO = (unsigned short*)(ws + 16777216);
    float* partial = (float*)(ws + 33554432);
    float* out = (float*)d_out;

    hipLaunchKernelGGL(k1_elem, dim3(BB * TT / 4), dim3(256), 0, stream, x, ema_mean, ema_sq,
                       ema_out, log_tau, log_beta_up, log_beta_dn, log_gamma, XN, PO);
    hipLaunchKernelGGL(k2_nn, dim3(BB * NTRI), dim3(256), 0, stream, XN, partial);
    hipLaunchKernelGGL(k3_scale, dim3(BB * TT / 4), dim3(256), 0, stream, out, PO, partial,
                       log_sigma_nn, log_w_nn);
}